// Round 3
// baseline (162.049 us; speedup 1.0000x reference)
//
#include <hip/hip_runtime.h>
#include <hip/hip_bf16.h>
#include <math.h>

#define IN_CH 512
#define HID   1024
#define NH    16
#define HD    64
#define BSZ   1024
#define KVB   2064
#define HC    129            // cols per head in out2
#define HCP   160            // padded cols per head (64k + 64v + 1lr + 15 zero)
#define LN_EPS 1e-5f

typedef short bf16x8 __attribute__((ext_vector_type(8)));
typedef float f32x4  __attribute__((ext_vector_type(4)));
typedef unsigned short u16;

__device__ inline u16 f2bf(float f) {                 // RNE bf16 bits
    unsigned u = __float_as_uint(f);
    unsigned r = u + 0x7FFFu + ((u >> 16) & 1u);
    return (u16)(r >> 16);
}
__device__ inline float bf2f(u16 u) {
    return __uint_as_float(((unsigned)u) << 16);
}

__device__ inline void gload16(const void* g, void* l) {
    __builtin_amdgcn_global_load_lds(
        (const __attribute__((address_space(1))) unsigned int*)g,
        (__attribute__((address_space(3))) unsigned int*)l, 16, 0, 0);
}

// ------------- conversions: x, w_in (straight) + w_kvb (per-head padded) -----
#define QX (BSZ * IN_CH / 4)              // 131072
#define QW (HID * IN_CH / 4)              // 131072
#define QK2 (NH * HCP * HID / 4)          // 655360
#define TOTQ (QX + QW + QK2)              // 917504  (/256 = 3584 blocks)

__global__ __launch_bounds__(256) void cvt_all(const float* __restrict__ x,
                                               const float* __restrict__ w_in,
                                               const float* __restrict__ w_kvb,
                                               const float* __restrict__ b_kvb,
                                               u16* __restrict__ xh, u16* __restrict__ xl,
                                               u16* __restrict__ wih, u16* __restrict__ wil,
                                               u16* __restrict__ wkh, u16* __restrict__ wkl,
                                               float* __restrict__ bias2) {
    long q = (long)blockIdx.x * 256 + threadIdx.x;
    if (q >= TOTQ) {                      // one trailing block: bias rearrange
        for (int i = threadIdx.x; i < NH * HCP; i += 256) {
            int head = i / HCP, c = i - head * HCP;
            bias2[i] = (c < HC) ? b_kvb[head * HC + c] : 0.f;
        }
        return;
    }
    float4 v;
    u16 *ph, *pl; long lq;
    if (q < QX) {
        lq = q; ph = xh; pl = xl;
        v = ((const float4*)x)[lq];
    } else if (q < QX + QW) {
        lq = q - QX; ph = wih; pl = wil;
        v = ((const float4*)w_in)[lq];
    } else {
        lq = q - QX - QW; ph = wkh; pl = wkl;
        int kq   = (int)(lq & 255);           // K/4 = 256 quads per row
        int rp   = (int)(lq >> 8);            // 0..2559
        int head = rp / HCP;
        int rowp = rp - head * HCP;
        if (rowp < HC)
            v = ((const float4*)w_kvb)[(size_t)(head * HC + rowp) * 256 + kq];
        else
            v = make_float4(0.f, 0.f, 0.f, 0.f);
    }
    float f[4] = {v.x, v.y, v.z, v.w};
    ushort4 hh4, ll4;
    u16 hb[4], lb[4];
    #pragma unroll
    for (int j = 0; j < 4; ++j) {
        hb[j] = f2bf(f[j]);
        lb[j] = f2bf(f[j] - bf2f(hb[j]));
    }
    hh4.x = hb[0]; hh4.y = hb[1]; hh4.z = hb[2]; hh4.w = hb[3];
    ll4.x = lb[0]; ll4.y = lb[1]; ll4.z = lb[2]; ll4.w = lb[3];
    ((ushort4*)ph)[lq] = hh4;
    ((ushort4*)pl)[lq] = ll4;
}

// ------------- GEMM1 (split precision, 64x64 tile): h = x @ w_in^T + b_in ----
__global__ __launch_bounds__(256) void gemm1(const u16* __restrict__ Ah_g,
                                             const u16* __restrict__ Al_g,
                                             const u16* __restrict__ Bh_g,
                                             const u16* __restrict__ Bl_g,
                                             const float* __restrict__ bias,
                                             float* __restrict__ C) {
    const int BM = 64, BN = 64, K = IN_CH, ldc = HID;
    __shared__ __align__(16) u16 Ah[2][64][32];
    __shared__ __align__(16) u16 Al[2][64][32];
    __shared__ __align__(16) u16 Bh[2][64][32];
    __shared__ __align__(16) u16 Bl[2][64][32];

    const int t = threadIdx.x, lane = t & 63, wid = t >> 6;
    const int wm = wid >> 1, wn = wid & 1;
    const int m0 = blockIdx.y * BM, n0 = blockIdx.x * BN;

    f32x4 acc[2][2] = {};

    auto stage = [&](int buf, int k0) {
        int row = wid * 16 + (lane >> 2);
        int seg = (lane & 3) ^ (row & 3);
        size_t goA = (size_t)(m0 + row) * K + k0 + seg * 8;
        size_t goB = (size_t)(n0 + row) * K + k0 + seg * 8;
        gload16(Ah_g + goA, &Ah[buf][wid * 16][0]);
        gload16(Al_g + goA, &Al[buf][wid * 16][0]);
        gload16(Bh_g + goB, &Bh[buf][wid * 16][0]);
        gload16(Bl_g + goB, &Bl[buf][wid * 16][0]);
    };

    const int KT = K / 32;
    stage(0, 0);
    __syncthreads();
    int buf = 0;
    for (int kt = 0; kt < KT; ++kt) {
        if (kt + 1 < KT) stage(buf ^ 1, (kt + 1) * 32);

        bf16x8 ah[2], al[2], bh[2], bl[2];
        #pragma unroll
        for (int mf = 0; mf < 2; ++mf) {
            int r = wm * 32 + mf * 16 + (lane & 15);
            int c = (lane >> 4) ^ (r & 3);
            ah[mf] = *(const bf16x8*)&Ah[buf][r][c * 8];
            al[mf] = *(const bf16x8*)&Al[buf][r][c * 8];
        }
        #pragma unroll
        for (int nf = 0; nf < 2; ++nf) {
            int r = wn * 32 + nf * 16 + (lane & 15);
            int c = (lane >> 4) ^ (r & 3);
            bh[nf] = *(const bf16x8*)&Bh[buf][r][c * 8];
            bl[nf] = *(const bf16x8*)&Bl[buf][r][c * 8];
        }
        #pragma unroll
        for (int mf = 0; mf < 2; ++mf)
            #pragma unroll
            for (int nf = 0; nf < 2; ++nf) {
                acc[mf][nf] = __builtin_amdgcn_mfma_f32_16x16x32_bf16(ah[mf], bh[nf], acc[mf][nf], 0, 0, 0);
                acc[mf][nf] = __builtin_amdgcn_mfma_f32_16x16x32_bf16(ah[mf], bl[nf], acc[mf][nf], 0, 0, 0);
                acc[mf][nf] = __builtin_amdgcn_mfma_f32_16x16x32_bf16(al[mf], bh[nf], acc[mf][nf], 0, 0, 0);
            }
        __syncthreads();
        buf ^= 1;
    }

    #pragma unroll
    for (int mf = 0; mf < 2; ++mf)
        #pragma unroll
        for (int nf = 0; nf < 2; ++nf) {
            int col = n0 + wn * 32 + nf * 16 + (lane & 15);
            float bb = bias[col];
            #pragma unroll
            for (int r = 0; r < 4; ++r) {
                int row = m0 + wm * 32 + mf * 16 + ((lane >> 4) << 2) + r;
                C[(size_t)row * ldc + col] = acc[mf][nf][r] + bb;
            }
        }
}

// ------------- LayerNorm rows of h -> bf16 hi/lo ------------------------------
__global__ __launch_bounds__(256) void ln_rows(const float* __restrict__ h,
                                               const float* __restrict__ gamma,
                                               const float* __restrict__ beta,
                                               u16* __restrict__ hh,
                                               u16* __restrict__ hl) {
    const int row = blockIdx.x;
    const int t   = threadIdx.x;
    const float* hr = h + (size_t)row * HID;

    float4 v = *(const float4*)(hr + t * 4);
    float s  = v.x + v.y + v.z + v.w;
    float sq = v.x * v.x + v.y * v.y + v.z * v.z + v.w * v.w;

    #pragma unroll
    for (int off = 1; off < 64; off <<= 1) {
        s  += __shfl_xor(s, off);
        sq += __shfl_xor(sq, off);
    }
    __shared__ float red[8];
    const int wid = t >> 6;
    if ((t & 63) == 0) { red[wid] = s; red[4 + wid] = sq; }
    __syncthreads();
    s  = red[0] + red[1] + red[2] + red[3];
    sq = red[4] + red[5] + red[6] + red[7];

    const float mu  = s * (1.f / HID);
    const float var = sq * (1.f / HID) - mu * mu;
    const float inv = rsqrtf(var + LN_EPS);

    float4 g  = *(const float4*)(gamma + t * 4);
    float4 be = *(const float4*)(beta + t * 4);
    float o[4];
    o[0] = (v.x - mu) * inv * g.x + be.x;
    o[1] = (v.y - mu) * inv * g.y + be.y;
    o[2] = (v.z - mu) * inv * g.z + be.z;
    o[3] = (v.w - mu) * inv * g.w + be.w;

    ushort4 uh, ul;
    u16 hb[4], lb[4];
    #pragma unroll
    for (int j = 0; j < 4; ++j) {
        hb[j] = f2bf(o[j]);
        lb[j] = f2bf(o[j] - bf2f(hb[j]));
    }
    uh.x = hb[0]; uh.y = hb[1]; uh.z = hb[2]; uh.w = hb[3];
    ul.x = lb[0]; ul.y = lb[1]; ul.z = lb[2]; ul.w = lb[3];
    ((ushort4*)(hh + (size_t)row * HID))[t] = uh;
    ((ushort4*)(hl + (size_t)row * HID))[t] = ul;
}

// ------------- FUSED: out2 tile (MFMA) -> LDS -> tail (W stream) --------------
// Block = (head, 32 batch rows). 256 thr = 4 waves, 2x2: WM=16, WN=80 (NF=5).
struct Smem {
    u16 Ah[2][32][32];    // 4 KB
    u16 Al[2][32][32];    // 4 KB
    u16 Bh[2][HCP][32];   // 20 KB   (aliased as out tile 32x160 f32 after GEMM)
    u16 Bl[2][HCP][32];   // 20 KB
};

__global__ __launch_bounds__(256, 3) void gemm2_tail(const u16* __restrict__ hh,
                                                     const u16* __restrict__ hl,
                                                     const u16* __restrict__ wkh,
                                                     const u16* __restrict__ wkl,
                                                     const float* __restrict__ bias2,
                                                     const float* __restrict__ W,
                                                     float* __restrict__ dW) {
    __shared__ Smem sm;
    const int t = threadIdx.x, lane = t & 63, wid = t >> 6;
    const int wm = wid >> 1, wn = wid & 1;
    const int head = blockIdx.x;
    const int m0   = blockIdx.y * 32;
    const int K = HID;

    f32x4 acc[5] = {};

    auto stage = [&](int buf, int k0) {
        #pragma unroll
        for (int it = 0; it < 3; ++it) {
            int u = it * 4 + wid;                 // 12 wave-units: 2 A + 10 B
            if (u < 2) {
                int c   = u * 64 + lane;          // A chunk (32 rows x 4)
                int row = c >> 2;
                int seg = (c & 3) ^ (row & 3);
                size_t go = (size_t)(m0 + row) * K + k0 + seg * 8;
                gload16(hh + go, &sm.Ah[buf][u * 16][0]);
                gload16(hl + go, &sm.Al[buf][u * 16][0]);
            } else {
                int bu  = u - 2;                  // B chunk (160 rows x 4)
                int c   = bu * 64 + lane;
                int row = c >> 2;
                int seg = (c & 3) ^ (row & 3);
                size_t go = (size_t)(head * HCP + row) * K + k0 + seg * 8;
                gload16(wkh + go, &sm.Bh[buf][bu * 16][0]);
                gload16(wkl + go, &sm.Bl[buf][bu * 16][0]);
            }
        }
    };

    const int KT = K / 32;                        // 32
    stage(0, 0);
    __syncthreads();
    int buf = 0;
    for (int kt = 0; kt < KT; ++kt) {
        if (kt + 1 < KT) stage(buf ^ 1, (kt + 1) * 32);

        bf16x8 ah, al, bh[5], bl[5];
        {
            int r = wm * 16 + (lane & 15);
            int c = (lane >> 4) ^ (r & 3);
            ah = *(const bf16x8*)&sm.Ah[buf][r][c * 8];
            al = *(const bf16x8*)&sm.Al[buf][r][c * 8];
        }
        #pragma unroll
        for (int nf = 0; nf < 5; ++nf) {
            int r = wn * 80 + nf * 16 + (lane & 15);
            int c = (lane >> 4) ^ (r & 3);
            bh[nf] = *(const bf16x8*)&sm.Bh[buf][r][c * 8];
            bl[nf] = *(const bf16x8*)&sm.Bl[buf][r][c * 8];
        }
        #pragma unroll
        for (int nf = 0; nf < 5; ++nf) {
            acc[nf] = __builtin_amdgcn_mfma_f32_16x16x32_bf16(ah, bh[nf], acc[nf], 0, 0, 0);
            acc[nf] = __builtin_amdgcn_mfma_f32_16x16x32_bf16(ah, bl[nf], acc[nf], 0, 0, 0);
            acc[nf] = __builtin_amdgcn_mfma_f32_16x16x32_bf16(al, bh[nf], acc[nf], 0, 0, 0);
        }
        __syncthreads();
        buf ^= 1;
    }

    // out tile -> LDS (aliases B staging, which is dead now)
    float* outLds = (float*)&sm.Bh[0][0][0];      // 32 x 160 f32 = 20 KB
    #pragma unroll
    for (int nf = 0; nf < 5; ++nf) {
        int col = wn * 80 + nf * 16 + (lane & 15);
        float bb = bias2[head * HCP + col];
        #pragma unroll
        for (int r = 0; r < 4; ++r) {
            int row = wm * 16 + ((lane >> 4) << 2) + r;
            outLds[row * HCP + col] = acc[nf][r] + bb;
        }
    }
    __syncthreads();

    // tail: each wave handles 8 (b, head) pairs
    const int g   = lane >> 4;
    const int c16 = lane & 15;
    for (int rr = 0; rr < 8; ++rr) {
        const int row  = wid * 8 + rr;
        const float kin   = outLds[row * HCP + lane];
        const float vfull = tanhf(outLds[row * HCP + 64 + lane]);
        const float lrl   = outLds[row * HCP + 128];
        const float lr    = 1.f / (1.f + expf(-lrl));

        const int pair = (m0 + row) * NH + head;
        const float* wbh = W + (size_t)pair * (HD * HD);

        float rem[4] = {0.f, 0.f, 0.f, 0.f};
        #pragma unroll
        for (int tt = 0; tt < 16; ++tt) {
            const int i = 4 * tt + g;
            const float vsi = __shfl(vfull, i);
            float4 w4 = *(const float4*)(wbh + i * 64 + c16 * 4);
            rem[0] = fmaf(w4.x, vsi, rem[0]);
            rem[1] = fmaf(w4.y, vsi, rem[1]);
            rem[2] = fmaf(w4.z, vsi, rem[2]);
            rem[3] = fmaf(w4.w, vsi, rem[3]);
        }
        #pragma unroll
        for (int q = 0; q < 4; ++q) {
            rem[q] += __shfl_xor(rem[q], 16);
            rem[q] += __shfl_xor(rem[q], 32);
        }

        float L[4];
        #pragma unroll
        for (int q = 0; q < 4; ++q)
            L[q] = __shfl(kin, 4 * c16 + q) - rem[q];

        float mx = fmaxf(fmaxf(L[0], L[1]), fmaxf(L[2], L[3]));
        #pragma unroll
        for (int off = 1; off < 16; off <<= 1)
            mx = fmaxf(mx, __shfl_xor(mx, off));

        float e[4], ssum = 0.f;
        #pragma unroll
        for (int q = 0; q < 4; ++q) { e[q] = expf(L[q] - mx); ssum += e[q]; }
        #pragma unroll
        for (int off = 1; off < 16; off <<= 1)
            ssum += __shfl_xor(ssum, off);

        const float scale = lr / ssum;
        float ks[4];
        #pragma unroll
        for (int q = 0; q < 4; ++q) ks[q] = e[q] * scale;

        float* obh = dW + (size_t)pair * (HD * HD);
        #pragma unroll
        for (int tt = 0; tt < 16; ++tt) {
            const int i = 4 * tt + g;
            const float vsi = __shfl(vfull, i);
            float4 o = make_float4(vsi * ks[0], vsi * ks[1], vsi * ks[2], vsi * ks[3]);
            *(float4*)(obh + i * 64 + c16 * 4) = o;
        }
    }
}

extern "C" void kernel_launch(void* const* d_in, const int* in_sizes, int n_in,
                              void* d_out, int out_size, void* d_ws, size_t ws_size,
                              hipStream_t stream) {
    const float* x     = (const float*)d_in[0];
    const float* W     = (const float*)d_in[1];
    const float* w_in  = (const float*)d_in[2];
    const float* b_in  = (const float*)d_in[3];
    const float* gamma = (const float*)d_in[4];
    const float* beta  = (const float*)d_in[5];
    const float* w_kvb = (const float*)d_in[6];
    const float* b_kvb = (const float*)d_in[7];
    float* dW = (float*)d_out;

    char* p = (char*)d_ws;
    auto carve = [&](size_t bytes) { char* r = p; p += (bytes + 255) & ~(size_t)255; return r; };
    float* h     = (float*)carve((size_t)BSZ * HID * 4);
    u16* xh  = (u16*)carve((size_t)BSZ * IN_CH * 2);
    u16* xl  = (u16*)carve((size_t)BSZ * IN_CH * 2);
    u16* wih = (u16*)carve((size_t)HID * IN_CH * 2);
    u16* wil = (u16*)carve((size_t)HID * IN_CH * 2);
    u16* hh  = (u16*)carve((size_t)BSZ * HID * 2);
    u16* hl  = (u16*)carve((size_t)BSZ * HID * 2);
    u16* wkh = (u16*)carve((size_t)NH * HCP * HID * 2);
    u16* wkl = (u16*)carve((size_t)NH * HCP * HID * 2);
    float* bias2 = (float*)carve((size_t)NH * HCP * 4);

    // conversions + w_kvb/bias per-head rearrange (one extra block for bias)
    cvt_all<<<TOTQ / 256 + 1, 256, 0, stream>>>(x, w_in, w_kvb, b_kvb,
                                                xh, xl, wih, wil, wkh, wkl, bias2);

    // h = x @ w_in^T + b_in   (M=1024, N=1024, K=512)
    gemm1<<<dim3(HID / 64, BSZ / 64), 256, 0, stream>>>(xh, xl, wih, wil, b_in, h);

    // LayerNorm + hi/lo convert
    ln_rows<<<BSZ, 256, 0, stream>>>(h, gamma, beta, hh, hl);

    // fused GEMM2 + tail
    gemm2_tail<<<dim3(NH, BSZ / 32), 256, 0, stream>>>(hh, hl, wkh, wkl, bias2, W, dW);
}

// Round 4
// 151.207 us; speedup vs baseline: 1.0717x; 1.0717x over previous
//
#include <hip/hip_runtime.h>
#include <hip/hip_bf16.h>
#include <math.h>

#define IN_CH 512
#define HID   1024
#define NH    16
#define HD    64
#define BSZ   1024
#define KVB   2064
#define NPAD  2112
#define LN_EPS 1e-5f

typedef _Float16 f16x8 __attribute__((ext_vector_type(8)));
typedef float f32x4  __attribute__((ext_vector_type(4)));
typedef unsigned short u16;

__device__ inline void split16(float f, u16& hi, u16& lo) {
    _Float16 h = (_Float16)f;
    _Float16 l = (_Float16)(f - (float)h);
    hi = __builtin_bit_cast(u16, h);
    lo = __builtin_bit_cast(u16, l);
}
__device__ inline u16 f2h(float f) {
    _Float16 h = (_Float16)f;
    return __builtin_bit_cast(u16, h);
}

__device__ inline void gload16(const void* g, void* l) {
    __builtin_amdgcn_global_load_lds(
        (const __attribute__((address_space(1))) unsigned int*)g,
        (__attribute__((address_space(3))) unsigned int*)l, 16, 0, 0);
}

// ------------- conversions: x -> (xh,xl) fp16; w_in -> wih; w_kvb -> wkh -----
#define QX (BSZ * IN_CH / 4)              // 131072
#define QW (HID * IN_CH / 4)              // 131072
#define QK (NPAD * HID / 4)               // 540672
#define QKVALID (KVB * HID / 4)           // 528384
#define TOTQ (QX + QW + QK)               // 802816 -> 3136 blocks

__global__ __launch_bounds__(256) void cvt_all(const float* __restrict__ x,
                                               const float* __restrict__ w_in,
                                               const float* __restrict__ w_kvb,
                                               u16* __restrict__ xh, u16* __restrict__ xl,
                                               u16* __restrict__ wih,
                                               u16* __restrict__ wkh) {
    long q = (long)blockIdx.x * 256 + threadIdx.x;
    if (q < QX) {
        float4 v = ((const float4*)x)[q];
        float f[4] = {v.x, v.y, v.z, v.w};
        ushort4 hh4, ll4;
        u16 hb[4], lb[4];
        #pragma unroll
        for (int j = 0; j < 4; ++j) split16(f[j], hb[j], lb[j]);
        hh4.x = hb[0]; hh4.y = hb[1]; hh4.z = hb[2]; hh4.w = hb[3];
        ll4.x = lb[0]; ll4.y = lb[1]; ll4.z = lb[2]; ll4.w = lb[3];
        ((ushort4*)xh)[q] = hh4;
        ((ushort4*)xl)[q] = ll4;
    } else if (q < QX + QW) {
        long lq = q - QX;
        float4 v = ((const float4*)w_in)[lq];
        ushort4 hh4;
        hh4.x = f2h(v.x); hh4.y = f2h(v.y); hh4.z = f2h(v.z); hh4.w = f2h(v.w);
        ((ushort4*)wih)[lq] = hh4;
    } else {
        long lq = q - QX - QW;
        float4 v = (lq < QKVALID) ? ((const float4*)w_kvb)[lq]
                                  : make_float4(0.f, 0.f, 0.f, 0.f);
        ushort4 hh4;
        hh4.x = f2h(v.x); hh4.y = f2h(v.y); hh4.z = f2h(v.z); hh4.w = f2h(v.w);
        ((ushort4*)wkh)[lq] = hh4;
    }
}

// ------------- fp16 2-term split GEMM:  C = A @ B^T + bias -------------------
// A = (Ah + Al) fp16 pair, B = Bh fp16 single.  256 thr = 4 waves (2x2).
template<int BM, int BN, int KK>
__global__ __launch_bounds__(256) void gemm_f16(const u16* __restrict__ Ah_g,
                                                const u16* __restrict__ Al_g,
                                                const u16* __restrict__ Bh_g,
                                                const float* __restrict__ bias,
                                                float* __restrict__ C,
                                                int N, int ldc) {
    constexpr int WM = BM / 2, WN = BN / 2, MF = WM / 16, NF = WN / 16;
    constexpr int AU = BM / 16;             // gload units per A array
    constexpr int U  = 2 * AU + BN / 16;    // total wave-units per K-step
    __shared__ __align__(16) u16 Ah[2][BM][32];
    __shared__ __align__(16) u16 Al[2][BM][32];
    __shared__ __align__(16) u16 Bh[2][BN][32];

    const int t = threadIdx.x, lane = t & 63, wid = t >> 6;
    const int wm = wid >> 1, wn = wid & 1;
    const int m0 = blockIdx.y * BM, n0 = blockIdx.x * BN;

    f32x4 acc[MF][NF] = {};

    auto stage = [&](int buf, int k0) {
        #pragma unroll
        for (int it = 0; it < U / 4; ++it) {
            int u = it * 4 + wid;
            if (u < AU) {
                int c = u * 64 + lane, row = c >> 2, seg = (c & 3) ^ (row & 3);
                gload16(Ah_g + (size_t)(m0 + row) * KK + k0 + seg * 8,
                        &Ah[buf][u * 16][0]);
            } else if (u < 2 * AU) {
                int uu = u - AU;
                int c = uu * 64 + lane, row = c >> 2, seg = (c & 3) ^ (row & 3);
                gload16(Al_g + (size_t)(m0 + row) * KK + k0 + seg * 8,
                        &Al[buf][uu * 16][0]);
            } else {
                int bu = u - 2 * AU;
                int c = bu * 64 + lane, row = c >> 2, seg = (c & 3) ^ (row & 3);
                gload16(Bh_g + (size_t)(n0 + row) * KK + k0 + seg * 8,
                        &Bh[buf][bu * 16][0]);
            }
        }
    };

    constexpr int KT = KK / 32;
    stage(0, 0);
    __syncthreads();
    int buf = 0;
    for (int kt = 0; kt < KT; ++kt) {
        if (kt + 1 < KT) stage(buf ^ 1, (kt + 1) * 32);

        f16x8 ah[MF], al[MF], bh[NF];
        #pragma unroll
        for (int mf = 0; mf < MF; ++mf) {
            int r = wm * WM + mf * 16 + (lane & 15);
            int c = (lane >> 4) ^ (r & 3);
            ah[mf] = *(const f16x8*)&Ah[buf][r][c * 8];
            al[mf] = *(const f16x8*)&Al[buf][r][c * 8];
        }
        #pragma unroll
        for (int nf = 0; nf < NF; ++nf) {
            int r = wn * WN + nf * 16 + (lane & 15);
            int c = (lane >> 4) ^ (r & 3);
            bh[nf] = *(const f16x8*)&Bh[buf][r][c * 8];
        }
        #pragma unroll
        for (int mf = 0; mf < MF; ++mf)
            #pragma unroll
            for (int nf = 0; nf < NF; ++nf) {
                acc[mf][nf] = __builtin_amdgcn_mfma_f32_16x16x32_f16(ah[mf], bh[nf], acc[mf][nf], 0, 0, 0);
                acc[mf][nf] = __builtin_amdgcn_mfma_f32_16x16x32_f16(al[mf], bh[nf], acc[mf][nf], 0, 0, 0);
            }
        __syncthreads();
        buf ^= 1;
    }

    #pragma unroll
    for (int mf = 0; mf < MF; ++mf)
        #pragma unroll
        for (int nf = 0; nf < NF; ++nf) {
            int col = n0 + wn * WN + nf * 16 + (lane & 15);
            if (col < N) {
                float bb = bias[col];
                #pragma unroll
                for (int r = 0; r < 4; ++r) {
                    int row = m0 + wm * WM + mf * 16 + ((lane >> 4) << 2) + r;
                    C[(size_t)row * ldc + col] = acc[mf][nf][r] + bb;
                }
            }
        }
}

// ------------- LayerNorm rows of h -> fp16 hi/lo ------------------------------
__global__ __launch_bounds__(256) void ln_rows(const float* __restrict__ h,
                                               const float* __restrict__ gamma,
                                               const float* __restrict__ beta,
                                               u16* __restrict__ hh,
                                               u16* __restrict__ hl) {
    const int row = blockIdx.x;
    const int t   = threadIdx.x;
    const float* hr = h + (size_t)row * HID;

    float4 v = *(const float4*)(hr + t * 4);
    float s  = v.x + v.y + v.z + v.w;
    float sq = v.x * v.x + v.y * v.y + v.z * v.z + v.w * v.w;

    #pragma unroll
    for (int off = 1; off < 64; off <<= 1) {
        s  += __shfl_xor(s, off);
        sq += __shfl_xor(sq, off);
    }
    __shared__ float red[8];
    const int wid = t >> 6;
    if ((t & 63) == 0) { red[wid] = s; red[4 + wid] = sq; }
    __syncthreads();
    s  = red[0] + red[1] + red[2] + red[3];
    sq = red[4] + red[5] + red[6] + red[7];

    const float mu  = s * (1.f / HID);
    const float var = sq * (1.f / HID) - mu * mu;
    const float inv = rsqrtf(var + LN_EPS);

    float4 g  = *(const float4*)(gamma + t * 4);
    float4 be = *(const float4*)(beta + t * 4);
    float o[4];
    o[0] = (v.x - mu) * inv * g.x + be.x;
    o[1] = (v.y - mu) * inv * g.y + be.y;
    o[2] = (v.z - mu) * inv * g.z + be.z;
    o[3] = (v.w - mu) * inv * g.w + be.w;

    ushort4 uh, ul;
    u16 hb[4], lb[4];
    #pragma unroll
    for (int j = 0; j < 4; ++j) split16(o[j], hb[j], lb[j]);
    uh.x = hb[0]; uh.y = hb[1]; uh.z = hb[2]; uh.w = hb[3];
    ul.x = lb[0]; ul.y = lb[1]; ul.z = lb[2]; ul.w = lb[3];
    ((ushort4*)(hh + (size_t)row * HID))[t] = uh;
    ((ushort4*)(hl + (size_t)row * HID))[t] = ul;
}

// ------------- tail: one wave per (b, head) -----------------------------------
__global__ __launch_bounds__(256) void oja_tail(const float* __restrict__ out2,
                                                const float* __restrict__ W,
                                                float* __restrict__ dW) {
    const int lane = threadIdx.x & 63;
    const int wid  = threadIdx.x >> 6;
    const int pair = blockIdx.x * 4 + wid;      // b*16 + head
    const int b    = pair >> 4;
    const int head = pair & 15;

    const float* orow = out2 + (size_t)b * KVB + head * (2 * HD + 1);

    const float kin   = orow[lane];
    const float vfull = tanhf(orow[64 + lane]);
    float t3 = 0.f;
    if (lane == 0) t3 = orow[128];
    const float lrl = __shfl(t3, 0);
    const float lr  = 1.f / (1.f + expf(-lrl));

    const int g   = lane >> 4;
    const int c16 = lane & 15;

    const float* wbh = W + (size_t)pair * (HD * HD);

    float rem[4] = {0.f, 0.f, 0.f, 0.f};
    #pragma unroll
    for (int tt = 0; tt < 16; ++tt) {
        const int i = 4 * tt + g;
        const float vsi = __shfl(vfull, i);
        float4 w4 = *(const float4*)(wbh + i * 64 + c16 * 4);
        rem[0] = fmaf(w4.x, vsi, rem[0]);
        rem[1] = fmaf(w4.y, vsi, rem[1]);
        rem[2] = fmaf(w4.z, vsi, rem[2]);
        rem[3] = fmaf(w4.w, vsi, rem[3]);
    }
    #pragma unroll
    for (int q = 0; q < 4; ++q) {
        rem[q] += __shfl_xor(rem[q], 16);
        rem[q] += __shfl_xor(rem[q], 32);
    }

    float L[4];
    #pragma unroll
    for (int q = 0; q < 4; ++q)
        L[q] = __shfl(kin, 4 * c16 + q) - rem[q];

    float mx = fmaxf(fmaxf(L[0], L[1]), fmaxf(L[2], L[3]));
    #pragma unroll
    for (int off = 1; off < 16; off <<= 1)
        mx = fmaxf(mx, __shfl_xor(mx, off));

    float e[4], ssum = 0.f;
    #pragma unroll
    for (int q = 0; q < 4; ++q) { e[q] = expf(L[q] - mx); ssum += e[q]; }
    #pragma unroll
    for (int off = 1; off < 16; off <<= 1)
        ssum += __shfl_xor(ssum, off);

    const float scale = lr / ssum;
    float ks[4];
    #pragma unroll
    for (int q = 0; q < 4; ++q) ks[q] = e[q] * scale;

    float* obh = dW + (size_t)pair * (HD * HD);
    #pragma unroll
    for (int tt = 0; tt < 16; ++tt) {
        const int i = 4 * tt + g;
        const float vsi = __shfl(vfull, i);
        float4 o = make_float4(vsi * ks[0], vsi * ks[1], vsi * ks[2], vsi * ks[3]);
        *(float4*)(obh + i * 64 + c16 * 4) = o;
    }
}

extern "C" void kernel_launch(void* const* d_in, const int* in_sizes, int n_in,
                              void* d_out, int out_size, void* d_ws, size_t ws_size,
                              hipStream_t stream) {
    const float* x     = (const float*)d_in[0];
    const float* W     = (const float*)d_in[1];
    const float* w_in  = (const float*)d_in[2];
    const float* b_in  = (const float*)d_in[3];
    const float* gamma = (const float*)d_in[4];
    const float* beta  = (const float*)d_in[5];
    const float* w_kvb = (const float*)d_in[6];
    const float* b_kvb = (const float*)d_in[7];
    float* dW = (float*)d_out;

    char* p = (char*)d_ws;
    auto carve = [&](size_t bytes) { char* r = p; p += (bytes + 255) & ~(size_t)255; return r; };
    float* h    = (float*)carve((size_t)BSZ * HID * 4);
    float* out2 = (float*)carve((size_t)BSZ * KVB * 4);
    u16* xh  = (u16*)carve((size_t)BSZ * IN_CH * 2);
    u16* xl  = (u16*)carve((size_t)BSZ * IN_CH * 2);
    u16* wih = (u16*)carve((size_t)HID * IN_CH * 2);
    u16* hh  = (u16*)carve((size_t)BSZ * HID * 2);
    u16* hl  = (u16*)carve((size_t)BSZ * HID * 2);
    u16* wkh = (u16*)carve((size_t)NPAD * HID * 2);

    // conversions (x split fp16; w_in, w_kvb single fp16; w_kvb padded rows)
    cvt_all<<<TOTQ / 256, 256, 0, stream>>>(x, w_in, w_kvb, xh, xl, wih, wkh);

    // h = x @ w_in^T + b_in   (M=1024, N=1024, K=512), 32x64 tiles -> 512 blocks
    gemm_f16<32, 64, IN_CH><<<dim3(HID / 64, BSZ / 32), 256, 0, stream>>>(
        xh, xl, wih, b_in, h, HID, HID);

    // LayerNorm + fp16 hi/lo convert
    ln_rows<<<BSZ, 256, 0, stream>>>(h, gamma, beta, hh, hl);

    // out2 = h @ w_kvb^T + b_kvb  (M=1024, N=2064 pad 2112, K=1024), 64x64 tiles
    gemm_f16<64, 64, HID><<<dim3(NPAD / 64, BSZ / 64), 256, 0, stream>>>(
        hh, hl, wkh, b_kvb, out2, KVB, KVB);

    // tail
    oja_tail<<<(BSZ * NH) / 4, 256, 0, stream>>>(out2, W, dW);
}

// Round 5
// 137.494 us; speedup vs baseline: 1.1786x; 1.0997x over previous
//
#include <hip/hip_runtime.h>
#include <hip/hip_bf16.h>
#include <math.h>

#define IN_CH 512
#define HID   1024
#define NH    16
#define HD    64
#define BSZ   1024
#define KVB   2064
#define NPAD  2112
#define LN_EPS 1e-5f

typedef _Float16 f16x8 __attribute__((ext_vector_type(8)));
typedef float f32x4  __attribute__((ext_vector_type(4)));
typedef unsigned short u16;

__device__ inline void split16(float f, u16& hi, u16& lo) {
    _Float16 h = (_Float16)f;
    _Float16 l = (_Float16)(f - (float)h);
    hi = __builtin_bit_cast(u16, h);
    lo = __builtin_bit_cast(u16, l);
}
__device__ inline u16 f2h(float f) {
    _Float16 h = (_Float16)f;
    return __builtin_bit_cast(u16, h);
}

__device__ inline void gload16(const void* g, void* l) {
    __builtin_amdgcn_global_load_lds(
        (const __attribute__((address_space(1))) unsigned int*)g,
        (__attribute__((address_space(3))) unsigned int*)l, 16, 0, 0);
}

// ------------- conversions: x -> (xh,xl) fp16; w_in -> wih; w_kvb -> wkh -----
#define QX (BSZ * IN_CH / 4)              // 131072
#define QW (HID * IN_CH / 4)              // 131072
#define QK (NPAD * HID / 4)               // 540672
#define QKVALID (KVB * HID / 4)           // 528384
#define TOTQ (QX + QW + QK)               // 802816 -> 3136 blocks

__global__ __launch_bounds__(256) void cvt_all(const float* __restrict__ x,
                                               const float* __restrict__ w_in,
                                               const float* __restrict__ w_kvb,
                                               u16* __restrict__ xh, u16* __restrict__ xl,
                                               u16* __restrict__ wih,
                                               u16* __restrict__ wkh) {
    long q = (long)blockIdx.x * 256 + threadIdx.x;
    if (q < QX) {
        float4 v = ((const float4*)x)[q];
        float f[4] = {v.x, v.y, v.z, v.w};
        ushort4 hh4, ll4;
        u16 hb[4], lb[4];
        #pragma unroll
        for (int j = 0; j < 4; ++j) split16(f[j], hb[j], lb[j]);
        hh4.x = hb[0]; hh4.y = hb[1]; hh4.z = hb[2]; hh4.w = hb[3];
        ll4.x = lb[0]; ll4.y = lb[1]; ll4.z = lb[2]; ll4.w = lb[3];
        ((ushort4*)xh)[q] = hh4;
        ((ushort4*)xl)[q] = ll4;
    } else if (q < QX + QW) {
        long lq = q - QX;
        float4 v = ((const float4*)w_in)[lq];
        ushort4 hh4;
        hh4.x = f2h(v.x); hh4.y = f2h(v.y); hh4.z = f2h(v.z); hh4.w = f2h(v.w);
        ((ushort4*)wih)[lq] = hh4;
    } else {
        long lq = q - QX - QW;
        float4 v = (lq < QKVALID) ? ((const float4*)w_kvb)[lq]
                                  : make_float4(0.f, 0.f, 0.f, 0.f);
        ushort4 hh4;
        hh4.x = f2h(v.x); hh4.y = f2h(v.y); hh4.z = f2h(v.z); hh4.w = f2h(v.w);
        ((ushort4*)wkh)[lq] = hh4;
    }
}

// ------------- fp16 2-term split GEMM, BK=64, XOR-swizzled LDS ---------------
// C = (Ah+Al) @ Bh^T + bias.  256 thr = 4 waves (2x2).
// LDS rows are 64 u16 (128 B) = 8 chunks of 16 B; logical chunk lc lives at
// physical chunk pc = lc ^ (row & 7).  Staging uses linear LDS dest (gload_lds)
// with pre-swizzled GLOBAL source; reads apply the same XOR.
template<int BM, int BN, int KK, bool SWZ>
__global__ __launch_bounds__(256) void gemm_f16(const u16* __restrict__ Ah_g,
                                                const u16* __restrict__ Al_g,
                                                const u16* __restrict__ Bh_g,
                                                const float* __restrict__ bias,
                                                float* __restrict__ C,
                                                int N, int ldc) {
    constexpr int WM = BM / 2, WN = BN / 2, MF = WM / 16, NF = WN / 16;
    constexpr int UA = BM / 8;              // gload units per A array (8 rows/unit)
    constexpr int UB = BN / 8;
    constexpr int U  = 2 * UA + UB;
    __shared__ __align__(16) u16 Ah[2][BM][64];
    __shared__ __align__(16) u16 Al[2][BM][64];
    __shared__ __align__(16) u16 Bh[2][BN][64];

    const int t = threadIdx.x, lane = t & 63, wid = t >> 6;
    const int wm = wid >> 1, wn = wid & 1;

    int mt, nt;
    if (SWZ) {
        // grid = (NPAD/BN) * (BSZ/BM), XCD-chunked bijective remap (nwg % 8 == 0)
        int bid = blockIdx.x;
        int nwg = gridDim.x;
        int w = (bid & 7) * (nwg >> 3) + (bid >> 3);
        mt = w & (BSZ / BM - 1);
        nt = w / (BSZ / BM);
    } else {
        nt = blockIdx.x; mt = blockIdx.y;
    }
    const int m0 = mt * BM, n0 = nt * BN;

    const int seg = (lane & 7) ^ (lane >> 3);      // pre-swizzled source chunk
    const int r8  = lane >> 3;                     // row within 8-row unit

    f32x4 acc[MF][NF] = {};

    auto stage = [&](int buf, int k0) {
        #pragma unroll
        for (int it = 0; it < U / 4; ++it) {
            int u = it * 4 + wid;
            if (u < UA) {
                int row = u * 8 + r8;
                gload16(Ah_g + (size_t)(m0 + row) * KK + k0 + seg * 8,
                        &Ah[buf][u * 8][0]);
            } else if (u < 2 * UA) {
                int uu = u - UA;
                int row = uu * 8 + r8;
                gload16(Al_g + (size_t)(m0 + row) * KK + k0 + seg * 8,
                        &Al[buf][uu * 8][0]);
            } else {
                int bu = u - 2 * UA;
                int row = bu * 8 + r8;
                gload16(Bh_g + (size_t)(n0 + row) * KK + k0 + seg * 8,
                        &Bh[buf][bu * 8][0]);
            }
        }
    };

    constexpr int KT = KK / 64;
    stage(0, 0);
    __syncthreads();
    int buf = 0;
    for (int kt = 0; kt < KT; ++kt) {
        if (kt + 1 < KT) stage(buf ^ 1, (kt + 1) * 64);

        f16x8 ah[2][MF], al[2][MF], bh[2][NF];
        #pragma unroll
        for (int s = 0; s < 2; ++s) {
            #pragma unroll
            for (int mf = 0; mf < MF; ++mf) {
                int r = wm * WM + mf * 16 + (lane & 15);
                int pc = ((s << 2) | (lane >> 4)) ^ (r & 7);
                ah[s][mf] = *(const f16x8*)&Ah[buf][r][pc * 8];
                al[s][mf] = *(const f16x8*)&Al[buf][r][pc * 8];
            }
            #pragma unroll
            for (int nf = 0; nf < NF; ++nf) {
                int r = wn * WN + nf * 16 + (lane & 15);
                int pc = ((s << 2) | (lane >> 4)) ^ (r & 7);
                bh[s][nf] = *(const f16x8*)&Bh[buf][r][pc * 8];
            }
        }
        #pragma unroll
        for (int s = 0; s < 2; ++s)
            #pragma unroll
            for (int mf = 0; mf < MF; ++mf)
                #pragma unroll
                for (int nf = 0; nf < NF; ++nf) {
                    acc[mf][nf] = __builtin_amdgcn_mfma_f32_16x16x32_f16(ah[s][mf], bh[s][nf], acc[mf][nf], 0, 0, 0);
                    acc[mf][nf] = __builtin_amdgcn_mfma_f32_16x16x32_f16(al[s][mf], bh[s][nf], acc[mf][nf], 0, 0, 0);
                }
        __syncthreads();
        buf ^= 1;
    }

    #pragma unroll
    for (int mf = 0; mf < MF; ++mf)
        #pragma unroll
        for (int nf = 0; nf < NF; ++nf) {
            int col = n0 + wn * WN + nf * 16 + (lane & 15);
            if (col < N) {
                float bb = bias[col];
                #pragma unroll
                for (int r = 0; r < 4; ++r) {
                    int row = m0 + wm * WM + mf * 16 + ((lane >> 4) << 2) + r;
                    C[(size_t)row * ldc + col] = acc[mf][nf][r] + bb;
                }
            }
        }
}

// ------------- LayerNorm rows of h -> fp16 hi/lo ------------------------------
__global__ __launch_bounds__(256) void ln_rows(const float* __restrict__ h,
                                               const float* __restrict__ gamma,
                                               const float* __restrict__ beta,
                                               u16* __restrict__ hh,
                                               u16* __restrict__ hl) {
    const int row = blockIdx.x;
    const int t   = threadIdx.x;
    const float* hr = h + (size_t)row * HID;

    float4 v = *(const float4*)(hr + t * 4);
    float s  = v.x + v.y + v.z + v.w;
    float sq = v.x * v.x + v.y * v.y + v.z * v.z + v.w * v.w;

    #pragma unroll
    for (int off = 1; off < 64; off <<= 1) {
        s  += __shfl_xor(s, off);
        sq += __shfl_xor(sq, off);
    }
    __shared__ float red[8];
    const int wid = t >> 6;
    if ((t & 63) == 0) { red[wid] = s; red[4 + wid] = sq; }
    __syncthreads();
    s  = red[0] + red[1] + red[2] + red[3];
    sq = red[4] + red[5] + red[6] + red[7];

    const float mu  = s * (1.f / HID);
    const float var = sq * (1.f / HID) - mu * mu;
    const float inv = rsqrtf(var + LN_EPS);

    float4 g  = *(const float4*)(gamma + t * 4);
    float4 be = *(const float4*)(beta + t * 4);
    float o[4];
    o[0] = (v.x - mu) * inv * g.x + be.x;
    o[1] = (v.y - mu) * inv * g.y + be.y;
    o[2] = (v.z - mu) * inv * g.z + be.z;
    o[3] = (v.w - mu) * inv * g.w + be.w;

    ushort4 uh, ul;
    u16 hb[4], lb[4];
    #pragma unroll
    for (int j = 0; j < 4; ++j) split16(o[j], hb[j], lb[j]);
    uh.x = hb[0]; uh.y = hb[1]; uh.z = hb[2]; uh.w = hb[3];
    ul.x = lb[0]; ul.y = lb[1]; ul.z = lb[2]; ul.w = lb[3];
    ((ushort4*)(hh + (size_t)row * HID))[t] = uh;
    ((ushort4*)(hl + (size_t)row * HID))[t] = ul;
}

// ------------- tail: one wave per (b, head); nontemporal W/dW streams ---------
__global__ __launch_bounds__(256) void oja_tail(const float* __restrict__ out2,
                                                const float* __restrict__ W,
                                                float* __restrict__ dW) {
    const int lane = threadIdx.x & 63;
    const int wid  = threadIdx.x >> 6;
    const int pair = blockIdx.x * 4 + wid;      // b*16 + head
    const int b    = pair >> 4;
    const int head = pair & 15;

    const float* orow = out2 + (size_t)b * KVB + head * (2 * HD + 1);

    const float kin   = orow[lane];
    const float vfull = tanhf(orow[64 + lane]);
    float t3 = 0.f;
    if (lane == 0) t3 = orow[128];
    const float lrl = __shfl(t3, 0);
    const float lr  = 1.f / (1.f + expf(-lrl));

    const int g   = lane >> 4;
    const int c16 = lane & 15;

    const f32x4* wbh = (const f32x4*)(W + (size_t)pair * (HD * HD));

    float rem[4] = {0.f, 0.f, 0.f, 0.f};
    #pragma unroll
    for (int tt = 0; tt < 16; ++tt) {
        const int i = 4 * tt + g;
        const float vsi = __shfl(vfull, i);
        f32x4 w4 = __builtin_nontemporal_load(wbh + i * 16 + c16);
        rem[0] = fmaf(w4[0], vsi, rem[0]);
        rem[1] = fmaf(w4[1], vsi, rem[1]);
        rem[2] = fmaf(w4[2], vsi, rem[2]);
        rem[3] = fmaf(w4[3], vsi, rem[3]);
    }
    #pragma unroll
    for (int q = 0; q < 4; ++q) {
        rem[q] += __shfl_xor(rem[q], 16);
        rem[q] += __shfl_xor(rem[q], 32);
    }

    float L[4];
    #pragma unroll
    for (int q = 0; q < 4; ++q)
        L[q] = __shfl(kin, 4 * c16 + q) - rem[q];

    float mx = fmaxf(fmaxf(L[0], L[1]), fmaxf(L[2], L[3]));
    #pragma unroll
    for (int off = 1; off < 16; off <<= 1)
        mx = fmaxf(mx, __shfl_xor(mx, off));

    float e[4], ssum = 0.f;
    #pragma unroll
    for (int q = 0; q < 4; ++q) { e[q] = expf(L[q] - mx); ssum += e[q]; }
    #pragma unroll
    for (int off = 1; off < 16; off <<= 1)
        ssum += __shfl_xor(ssum, off);

    const float scale = lr / ssum;
    float ks[4];
    #pragma unroll
    for (int q = 0; q < 4; ++q) ks[q] = e[q] * scale;

    f32x4* obh = (f32x4*)(dW + (size_t)pair * (HD * HD));
    #pragma unroll
    for (int tt = 0; tt < 16; ++tt) {
        const int i = 4 * tt + g;
        const float vsi = __shfl(vfull, i);
        f32x4 o;
        o[0] = vsi * ks[0]; o[1] = vsi * ks[1];
        o[2] = vsi * ks[2]; o[3] = vsi * ks[3];
        __builtin_nontemporal_store(o, obh + i * 16 + c16);
    }
}

extern "C" void kernel_launch(void* const* d_in, const int* in_sizes, int n_in,
                              void* d_out, int out_size, void* d_ws, size_t ws_size,
                              hipStream_t stream) {
    const float* x     = (const float*)d_in[0];
    const float* W     = (const float*)d_in[1];
    const float* w_in  = (const float*)d_in[2];
    const float* b_in  = (const float*)d_in[3];
    const float* gamma = (const float*)d_in[4];
    const float* beta  = (const float*)d_in[5];
    const float* w_kvb = (const float*)d_in[6];
    const float* b_kvb = (const float*)d_in[7];
    float* dW = (float*)d_out;

    char* p = (char*)d_ws;
    auto carve = [&](size_t bytes) { char* r = p; p += (bytes + 255) & ~(size_t)255; return r; };
    float* h    = (float*)carve((size_t)BSZ * HID * 4);
    float* out2 = (float*)carve((size_t)BSZ * KVB * 4);
    u16* xh  = (u16*)carve((size_t)BSZ * IN_CH * 2);
    u16* xl  = (u16*)carve((size_t)BSZ * IN_CH * 2);
    u16* wih = (u16*)carve((size_t)HID * IN_CH * 2);
    u16* hh  = (u16*)carve((size_t)BSZ * HID * 2);
    u16* hl  = (u16*)carve((size_t)BSZ * HID * 2);
    u16* wkh = (u16*)carve((size_t)NPAD * HID * 2);

    // conversions (x split fp16; w_in, w_kvb single fp16; w_kvb padded rows)
    cvt_all<<<TOTQ / 256, 256, 0, stream>>>(x, w_in, w_kvb, xh, xl, wih, wkh);

    // h = x @ w_in^T + b_in   (M=1024, N=1024, K=512), 32x64 tiles -> 512 blocks
    gemm_f16<32, 64, IN_CH, false><<<dim3(HID / 64, BSZ / 32), 256, 0, stream>>>(
        xh, xl, wih, b_in, h, HID, HID);

    // LayerNorm + fp16 hi/lo convert
    ln_rows<<<BSZ, 256, 0, stream>>>(h, gamma, beta, hh, hl);

    // out2 = h @ w_kvb^T + b_kvb  (M=1024, N=2064 pad 2112, K=1024)
    // 64x64 tiles -> 528 blocks, XCD-chunked swizzle (528 % 8 == 0)
    gemm_f16<64, 64, HID, true><<<(NPAD / 64) * (BSZ / 64), 256, 0, stream>>>(
        hh, hl, wkh, b_kvb, out2, KVB, KVB);

    // tail
    oja_tail<<<(BSZ * NH) / 4, 256, 0, stream>>>(out2, W, dW);
}